// Round 5
// baseline (515.427 us; speedup 1.0000x reference)
//
#include <hip/hip_runtime.h>
#include <hip/hip_bf16.h>

typedef __attribute__((ext_vector_type(8))) short short8;
typedef __attribute__((ext_vector_type(4))) float f32x4;

#define S_DIM 384
#define N_DIM 512
#define C_DIM 32
#define CZ_DIM 128
#define MROWS (S_DIM * C_DIM) /* 12288 */

__device__ __forceinline__ void async16(const void* g, void* l) {
  __builtin_amdgcn_global_load_lds(
      (const __attribute__((address_space(1))) void*)g,
      (__attribute__((address_space(3))) void*)l, 16, 0, 0);
}

// Kernel 1: LayerNorm + w_ab projection.
__global__ __launch_bounds__(256) void prep_kernel(
    const float* __restrict__ m_si, const float* __restrict__ ln_g,
    const float* __restrict__ ln_b, const float* __restrict__ w_ab,
    __hip_bfloat16* __restrict__ Abt, __hip_bfloat16* __restrict__ Bbt) {
  const int n = blockIdx.x * 256 + threadIdx.x;  // 0..511
  const int s = blockIdx.y;                      // 0..383
  const float* x = m_si + ((size_t)s * N_DIM + n) * C_DIM;

  float v[C_DIM];
#pragma unroll
  for (int i = 0; i < 8; ++i) {
    float4 t = ((const float4*)x)[i];
    v[4 * i + 0] = t.x; v[4 * i + 1] = t.y;
    v[4 * i + 2] = t.z; v[4 * i + 3] = t.w;
  }
  float sum = 0.f;
#pragma unroll
  for (int c = 0; c < C_DIM; ++c) sum += v[c];
  const float mu = sum * (1.f / 32.f);
  float sq = 0.f;
#pragma unroll
  for (int c = 0; c < C_DIM; ++c) { float d = v[c] - mu; sq += d * d; }
  const float rstd = rsqrtf(sq * (1.f / 32.f) + 1e-5f);

  float mn[C_DIM];
#pragma unroll
  for (int c = 0; c < C_DIM; ++c)
    mn[c] = (v[c] - mu) * rstd * ln_g[c] + ln_b[c];

#pragma unroll 4
  for (int d = 0; d < 32; ++d) {
    float aA = 0.f, aB = 0.f;
#pragma unroll
    for (int c = 0; c < C_DIM; ++c) {
      aA += mn[c] * w_ab[d * C_DIM + c];
      aB += mn[c] * w_ab[(d + 32) * C_DIM + c];
    }
    Abt[((size_t)(s * 32 + d)) * N_DIM + n] = __float2bfloat16(aA * (1.f / 512.f));
    Bbt[((size_t)(s * 32 + d)) * N_DIM + n] = __float2bfloat16(aB);
  }
}

// Kernel 2: w_final fp32 -> bf16 (128 x 1024)
__global__ __launch_bounds__(256) void conv_wf(const float* __restrict__ w_final,
                                               __hip_bfloat16* __restrict__ Wf) {
  const int i = blockIdx.x * 256 + threadIdx.x;
  Wf[i] = __float2bfloat16(w_final[i]);
}

// Kernel 3: fused outer-product GEMM (256x256 tile, K=512) + w_final epilogue.
// 512 threads = 8 waves (2M x 4N); per-wave output 128x64 = 8x4 16x16 frags.
// R5: m201-style FINE INTERLEAVE added to R4's 4-slot/depth-3/counted-vmcnt
// machinery. Each K-tile = 2 phases of 16 MFMA:
//   { ds_read next subtile | 2 glds stage -> s_barrier -> lgkmcnt(0) ->
//     setprio(1) 16xMFMA setprio(0) [-> vmcnt(N)] -> s_barrier }
// Register sets parity-alternate (even/odd tile) so phase-B's prefetch of the
// NEXT tile's A/B frags doesn't clobber the B frags phase-B's MFMAs consume.
// vmcnt(6) at end of phase A (tiles<=12; guards next-slot ds_reads in phase B,
// placed BEFORE the closing barrier so ALL waves certify their glds landed
// before ANY wave reads the slot); tail vmcnt 6/4/0 at t12/t13/t14.
__global__ __launch_bounds__(512, 2) void fused_opm(
    const __hip_bfloat16* __restrict__ Abt, const __hip_bfloat16* __restrict__ Bbt,
    const __hip_bfloat16* __restrict__ Wf, const float* __restrict__ b_final,
    float* __restrict__ out) {
  // 4 slots x (A[256][32] + B[256][32]) bf16 = 4 x 32KB = 128KB.
  // Epilogue reuses all 128KB as Oc[64 cells][1024] bf16 (slot-swizzled).
  __shared__ __align__(16) char smem[131072];

  const int tid = threadIdx.x;
  const int wave = tid >> 6;
  const int lane = tid & 63;
  const int fr = lane & 15;              // MFMA row/col-within-tile
  const int fq = lane >> 4;              // MFMA quad
  const int fqs = fq ^ ((fr >> 1) & 3);  // swizzled physical k-slot
  const int wr = wave >> 2;              // 0..1  (M)
  const int wc = wave & 3;               // 0..3  (N)
  const int bi = blockIdx.y, bj = blockIdx.x;

  const size_t m0 = (size_t)bi * 256;
  const size_t n0 = (size_t)bj * 256;

  const int srow = tid >> 2;                             // 0..127 (+128 2nd issue)
  const int sk = (((tid & 3) ^ ((tid >> 3) & 3)) * 8);   // pre-swizzled k offset
  const __hip_bfloat16* gA = Abt + (m0 + srow) * N_DIM + sk;
  const __hip_bfloat16* gB = Bbt + (n0 + srow) * N_DIM + sk;
  const int ldst = tid * 16;

  const f32x4 fzero = {0.f, 0.f, 0.f, 0.f};
  f32x4 acc[8][4];
#pragma unroll
  for (int i = 0; i < 8; ++i)
#pragma unroll
    for (int j = 0; j < 4; ++j) acc[i][j] = fzero;

  // --- staging halves (2 glds each): A both row-halves / B both row-halves ---
  auto stageA = [&](int kt) {
    char* base = smem + (kt & 3) * 32768;
    const int k0 = kt * 32;
    async16(gA + k0, base + ldst);                                 // A rows 0..127
    async16(gA + (size_t)128 * N_DIM + k0, base + 8192 + ldst);    // A rows 128..255
  };
  auto stageB = [&](int kt) {
    char* base = smem + (kt & 3) * 32768;
    const int k0 = kt * 32;
    async16(gB + k0, base + 16384 + ldst);                         // B rows 0..127
    async16(gB + (size_t)128 * N_DIM + k0, base + 24576 + ldst);   // B rows 128..255
  };

  // --- register-subtile loads ---
  auto ldXA = [&](short8* xa, short8* xb, const char* base) {  // A mt0-3 + B (8 rds)
    const __hip_bfloat16* As = (const __hip_bfloat16*)base;
    const __hip_bfloat16* Bs = (const __hip_bfloat16*)(base + 16384);
#pragma unroll
    for (int mt = 0; mt < 4; ++mt)
      xa[mt] = *(const short8*)(As + (wr * 128 + mt * 16 + fr) * 32 + fqs * 8);
#pragma unroll
    for (int nt = 0; nt < 4; ++nt)
      xb[nt] = *(const short8*)(Bs + (wc * 64 + nt * 16 + fr) * 32 + fqs * 8);
  };
  auto ldYA = [&](short8* ya, const char* base) {              // A mt4-7 (4 rds)
    const __hip_bfloat16* As = (const __hip_bfloat16*)base;
#pragma unroll
    for (int mt = 0; mt < 4; ++mt)
      ya[mt] = *(const short8*)(As + (wr * 128 + (mt + 4) * 16 + fr) * 32 + fqs * 8);
  };

  auto mfmaLo = [&](const short8* a4, const short8* b4) {  // acc rows 0..3
    __builtin_amdgcn_s_setprio(1);
#pragma unroll
    for (int mt = 0; mt < 4; ++mt)
#pragma unroll
      for (int nt = 0; nt < 4; ++nt)
        acc[mt][nt] = __builtin_amdgcn_mfma_f32_16x16x32_bf16(a4[mt], b4[nt],
                                                              acc[mt][nt], 0, 0, 0);
    __builtin_amdgcn_s_setprio(0);
  };
  auto mfmaHi = [&](const short8* a4, const short8* b4) {  // acc rows 4..7
    __builtin_amdgcn_s_setprio(1);
#pragma unroll
    for (int mt = 0; mt < 4; ++mt)
#pragma unroll
      for (int nt = 0; nt < 4; ++nt)
        acc[mt + 4][nt] = __builtin_amdgcn_mfma_f32_16x16x32_bf16(
            a4[mt], b4[nt], acc[mt + 4][nt], 0, 0, 0);
    __builtin_amdgcn_s_setprio(0);
  };

  auto barrier_ = [&] {
    __builtin_amdgcn_sched_barrier(0);
    __builtin_amdgcn_s_barrier();
    __builtin_amdgcn_sched_barrier(0);
  };
  auto lgkm0 = [&] {
    asm volatile("s_waitcnt lgkmcnt(0)" ::: "memory");
    __builtin_amdgcn_sched_barrier(0);
  };

  short8 xa0[4], xb0[4], ya0[4];
  short8 xa1[4], xb1[4], ya1[4];

  // One K-tile = two fine phases. Current set (xaC,xbC,yaC); next set (xaN,xbN).
  auto tile_body = [&](int kt, short8* xaC, short8* xbC, short8* yaC,
                       short8* xaN, short8* xbN, int vmN, bool doStage,
                       bool doNext) {
    const char* baseC = smem + (kt & 3) * 32768;
    // ---- phase A: MFMA lo-half on (xaC,xbC); prefetch yaC; stage A-halves ----
    ldYA(yaC, baseC);
    if (doStage) stageA(kt + 3);
    barrier_();
    lgkm0();
    mfmaLo(xaC, xbC);
    __builtin_amdgcn_sched_barrier(0);
    if (vmN == 6) {
      asm volatile("s_waitcnt vmcnt(6)" ::: "memory");   // tile kt+1 landed (mine)
    } else if (vmN == 4) {
      asm volatile("s_waitcnt vmcnt(4)" ::: "memory");
    } else if (vmN == 0) {
      asm volatile("s_waitcnt vmcnt(0)" ::: "memory");
    }
    barrier_();  // all waves certified tile kt+1 landed; slot reads now safe
    // ---- phase B: MFMA hi-half on (yaC,xbC); prefetch next tile's (xaN,xbN) ----
    if (doNext) ldXA(xaN, xbN, smem + ((kt + 1) & 3) * 32768);
    if (doStage) stageB(kt + 3);
    barrier_();
    lgkm0();
    mfmaHi(yaC, xbC);
    barrier_();
  };

  // Prologue: 3 K-tiles in flight (12 glds).
  stageA(0); stageB(0);
  stageA(1); stageB(1);
  stageA(2); stageB(2);
  asm volatile("s_waitcnt vmcnt(8)" ::: "memory");  // tile 0 landed (mine)
  __builtin_amdgcn_sched_barrier(0);
  barrier_();                                        // everyone's tile 0 landed
  ldXA(xa0, xb0, smem);                              // bootstrap tile-0 frags

  for (int i = 0; i < 6; ++i) {       // tiles 0..11: steady state
    const int kt = 2 * i;
    tile_body(kt, xa0, xb0, ya0, xa1, xb1, 6, true, true);
    tile_body(kt + 1, xa1, xb1, ya1, xa0, xb0, 6, true, true);
  }
  tile_body(12, xa0, xb0, ya0, xa1, xb1, 6, true, true);    // stages t15
  tile_body(13, xa1, xb1, ya1, xa0, xb0, 4, false, true);
  tile_body(14, xa0, xb0, ya0, xa1, xb1, 0, false, true);
  tile_body(15, xa1, xb1, ya1, xa0, xb0, -1, false, false);

  __syncthreads();  // all waves done with staging LDS; repurpose as Oc

  // ---- Epilogue phase 1: o-tile (fp32 acc) -> Oc LDS bf16, slot-swizzled ----
  __hip_bfloat16* Oc = (__hip_bfloat16*)smem;  // [64][1024]
#pragma unroll
  for (int mt = 0; mt < 8; ++mt) {
#pragma unroll
    for (int nt = 0; nt < 4; ++nt) {
      const int orow_b = wr * 128 + mt * 16 + fq * 4;
      const int ocol = wc * 64 + nt * 16 + fr;  // C/D map: col=lane&15
#pragma unroll
      for (int r = 0; r < 4; ++r) {             // row=(lane>>4)*4+reg
        const int orow = orow_b + r;
        const int cell = ((orow >> 5) << 3) + (ocol >> 5);  // i_loc*8 + j_loc
        const int kk = ((orow & 31) << 5) + (ocol & 31);    // c*32+d
        const int sw = ((((kk >> 3) ^ (cell & 7)) << 3) | (kk & 7));
        Oc[cell * 1024 + sw] = __float2bfloat16(acc[mt][nt][r]);
      }
    }
  }
  __syncthreads();

  // ---- Epilogue phase 2: Z[64 cells][128] = Oc[64][1024] @ Wf[128][1024]^T ----
  f32x4 zacc[4] = {fzero, fzero, fzero, fzero};
  const int mt2 = wave >> 1;
  const int ng = wave & 1;
  const int ocell = mt2 * 16 + fr;
  const int xr = fr & 7;
#pragma unroll 4
  for (int kk = 0; kk < 32; ++kk) {
    const short8 oa =
        *(const short8*)(Oc + ocell * 1024 + (((kk * 4 + fq) ^ xr) << 3));
#pragma unroll
    for (int nt2 = 0; nt2 < 4; ++nt2) {
      const short8 wb = *(const short8*)(
          Wf + (size_t)(ng * 64 + nt2 * 16 + fr) * 1024 + kk * 32 + fq * 8);
      zacc[nt2] = __builtin_amdgcn_mfma_f32_16x16x32_bf16(oa, wb, zacc[nt2], 0, 0, 0);
    }
  }

  // ---- Epilogue phase 3: z-write (+ b_final) ----
  const int i0 = bi * 8, j0 = bj * 8;
#pragma unroll
  for (int nt2 = 0; nt2 < 4; ++nt2) {
    const int zcol = ng * 64 + nt2 * 16 + fr;
    const float bz = b_final[zcol];
#pragma unroll
    for (int r = 0; r < 4; ++r) {
      const int cell = mt2 * 16 + fq * 4 + r;  // D row = cell index
      const int li = cell >> 3, lj = cell & 7;
      out[((size_t)(i0 + li) * S_DIM + (j0 + lj)) * CZ_DIM + zcol] = zacc[nt2][r] + bz;
    }
  }
}

extern "C" void kernel_launch(void* const* d_in, const int* in_sizes, int n_in,
                              void* d_out, int out_size, void* d_ws, size_t ws_size,
                              hipStream_t stream) {
  const float* m_si = (const float*)d_in[0];
  const float* ln_g = (const float*)d_in[1];
  const float* ln_b = (const float*)d_in[2];
  const float* w_ab = (const float*)d_in[3];
  const float* w_final = (const float*)d_in[4];
  const float* b_final = (const float*)d_in[5];
  float* out = (float*)d_out;

  char* ws = (char*)d_ws;
  __hip_bfloat16* Abt = (__hip_bfloat16*)ws;                                // 12.58 MB
  __hip_bfloat16* Bbt = (__hip_bfloat16*)(ws + (size_t)MROWS * N_DIM * 2);  // 12.58 MB
  __hip_bfloat16* Wf = (__hip_bfloat16*)(ws + (size_t)MROWS * N_DIM * 4);   // 256 KB

  prep_kernel<<<dim3(2, S_DIM), 256, 0, stream>>>(m_si, ln_g, ln_b, w_ab, Abt, Bbt);
  conv_wf<<<dim3((CZ_DIM * 1024) / 256), 256, 0, stream>>>(w_final, Wf);
  fused_opm<<<dim3(48, 48), 512, 0, stream>>>(Abt, Bbt, Wf, b_final, out);
}

// Round 6
// 468.463 us; speedup vs baseline: 1.1003x; 1.1003x over previous
//
#include <hip/hip_runtime.h>
#include <hip/hip_bf16.h>

typedef __attribute__((ext_vector_type(8))) short short8;
typedef __attribute__((ext_vector_type(4))) float f32x4;

#define S_DIM 384
#define N_DIM 512
#define C_DIM 32
#define CZ_DIM 128
#define MROWS (S_DIM * C_DIM)   /* 12288 */
#define NCELL (S_DIM * S_DIM)   /* 147456 */

__device__ __forceinline__ void async16(const void* g, void* l) {
  __builtin_amdgcn_global_load_lds(
      (const __attribute__((address_space(1))) void*)g,
      (__attribute__((address_space(3))) void*)l, 16, 0, 0);
}

// Kernel 1: LayerNorm + w_ab projection.
__global__ __launch_bounds__(256) void prep_kernel(
    const float* __restrict__ m_si, const float* __restrict__ ln_g,
    const float* __restrict__ ln_b, const float* __restrict__ w_ab,
    __hip_bfloat16* __restrict__ Abt, __hip_bfloat16* __restrict__ Bbt) {
  const int n = blockIdx.x * 256 + threadIdx.x;  // 0..511
  const int s = blockIdx.y;                      // 0..383
  const float* x = m_si + ((size_t)s * N_DIM + n) * C_DIM;

  float v[C_DIM];
#pragma unroll
  for (int i = 0; i < 8; ++i) {
    float4 t = ((const float4*)x)[i];
    v[4 * i + 0] = t.x; v[4 * i + 1] = t.y;
    v[4 * i + 2] = t.z; v[4 * i + 3] = t.w;
  }
  float sum = 0.f;
#pragma unroll
  for (int c = 0; c < C_DIM; ++c) sum += v[c];
  const float mu = sum * (1.f / 32.f);
  float sq = 0.f;
#pragma unroll
  for (int c = 0; c < C_DIM; ++c) { float d = v[c] - mu; sq += d * d; }
  const float rstd = rsqrtf(sq * (1.f / 32.f) + 1e-5f);

  float mn[C_DIM];
#pragma unroll
  for (int c = 0; c < C_DIM; ++c)
    mn[c] = (v[c] - mu) * rstd * ln_g[c] + ln_b[c];

#pragma unroll 4
  for (int d = 0; d < 32; ++d) {
    float aA = 0.f, aB = 0.f;
#pragma unroll
    for (int c = 0; c < C_DIM; ++c) {
      aA += mn[c] * w_ab[d * C_DIM + c];
      aB += mn[c] * w_ab[(d + 32) * C_DIM + c];
    }
    Abt[((size_t)(s * 32 + d)) * N_DIM + n] = __float2bfloat16(aA * (1.f / 512.f));
    Bbt[((size_t)(s * 32 + d)) * N_DIM + n] = __float2bfloat16(aB);
  }
}

// Kernel 2: w_final fp32 -> bf16 (128 x 1024)
__global__ __launch_bounds__(256) void conv_wf(const float* __restrict__ w_final,
                                               __hip_bfloat16* __restrict__ Wf) {
  const int i = blockIdx.x * 256 + threadIdx.x;
  Wf[i] = __float2bfloat16(w_final[i]);
}

// Kernel 3a (split path): main outer-product GEMM only. 128x128 tile, K=512,
// 4 waves 2x2, R3's proven dbuf loop + k-slot swizzle. Epilogue = direct bf16
// store of O[cell][c*32+d] to global (no LDS round trip). LDS = 32 KB -> 5 blk/CU.
// XCD band swizzle: each XCD owns a 12-row bi-band (A-panels 1.5 MB, L2-resident).
__global__ __launch_bounds__(256, 2) void opm_main(
    const __hip_bfloat16* __restrict__ Abt, const __hip_bfloat16* __restrict__ Bbt,
    __hip_bfloat16* __restrict__ Og) {
  __shared__ __align__(16) char smem[32768];

  const int tid = threadIdx.x;
  const int wave = tid >> 6;
  const int lane = tid & 63;
  const int fr = lane & 15;
  const int fq = lane >> 4;
  const int fqs = fq ^ ((fr >> 1) & 3);  // swizzled physical k-slot
  const int wr = wave >> 1, wc = wave & 1;

  // XCD-aware remap (9216 blocks, 9216%8==0 -> bijective).
  const int flat = blockIdx.y * 96 + blockIdx.x;
  const int xcd = flat & 7;
  const int idx = flat >> 3;          // 0..1151
  const int bi = xcd * 12 + idx % 12; // 12-row band per XCD
  const int bj = idx / 12;

  const size_t m0 = (size_t)bi * 128;
  const size_t n0 = (size_t)bj * 128;

  const int srow = tid >> 2;
  const int sk = (((tid & 3) ^ ((tid >> 3) & 3)) * 8);  // pre-swizzled k offset
  const __hip_bfloat16* gA = Abt + (m0 + srow) * N_DIM + sk;
  const __hip_bfloat16* gB = Bbt + (n0 + srow) * N_DIM + sk;
  const int ldst = tid * 16;

  const f32x4 fzero = {0.f, 0.f, 0.f, 0.f};
  f32x4 acc[4][4];
#pragma unroll
  for (int i = 0; i < 4; ++i)
#pragma unroll
    for (int j = 0; j < 4; ++j) acc[i][j] = fzero;

  auto stage = [&](int kt, char* base) {
    const int k0 = kt * 32;
    async16(gA + k0, base + ldst);
    async16(gA + (size_t)64 * N_DIM + k0, base + 4096 + ldst);
    async16(gB + k0, base + 8192 + ldst);
    async16(gB + (size_t)64 * N_DIM + k0, base + 12288 + ldst);
  };
  auto compute = [&](const char* base) {
    const __hip_bfloat16* As = (const __hip_bfloat16*)base;
    const __hip_bfloat16* Bs = (const __hip_bfloat16*)(base + 8192);
    short8 af[4], bfr[4];
#pragma unroll
    for (int mt = 0; mt < 4; ++mt)
      af[mt] = *(const short8*)(As + (wr * 64 + mt * 16 + fr) * 32 + fqs * 8);
#pragma unroll
    for (int nt = 0; nt < 4; ++nt)
      bfr[nt] = *(const short8*)(Bs + (wc * 64 + nt * 16 + fr) * 32 + fqs * 8);
#pragma unroll
    for (int mt = 0; mt < 4; ++mt)
#pragma unroll
      for (int nt = 0; nt < 4; ++nt)
        acc[mt][nt] = __builtin_amdgcn_mfma_f32_16x16x32_bf16(
            af[mt], bfr[nt], acc[mt][nt], 0, 0, 0);
  };

  char* buf0 = smem;
  char* buf1 = smem + 16384;
  stage(0, buf0);
  __syncthreads();
  for (int kt = 0; kt < 16; kt += 2) {
    stage(kt + 1, buf1);
    compute(buf0);
    __syncthreads();
    if (kt + 2 < 16) stage(kt + 2, buf0);
    compute(buf1);
    __syncthreads();
  }

  // O store: O[(gi*384+gj)*1024 + c*32 + d], bf16. Per 16-lane group the d-index
  // is contiguous -> 32 B segments; 64 scalar stores/thread.
#pragma unroll
  for (int mt = 0; mt < 4; ++mt) {
#pragma unroll
    for (int nt = 0; nt < 4; ++nt) {
      const int orow_b = wr * 64 + mt * 16 + fq * 4;      // m within 128-tile
      const int ocol = wc * 64 + nt * 16 + fr;            // n within 128-tile
      const int gi = bi * 4 + (orow_b >> 5);
      const int gj = bj * 4 + (ocol >> 5);
      const int d = ocol & 31;
      __hip_bfloat16* po =
          Og + ((size_t)(gi * S_DIM + gj)) * 1024 + ((orow_b & 31) << 5) + d;
#pragma unroll
      for (int r = 0; r < 4; ++r)
        po[r * 32] = __float2bfloat16(acc[mt][nt][r]);
    }
  }
}

// Kernel 3b (split path): Z[NCELL][128] = O[NCELL][1024] @ Wf[128][1024]^T + b.
// 1152 blocks x 256 thr (4 waves 2x2); tile 128 cells x 128 z; K=1024 in 32 steps.
// Same staging/swizzle/dbuf structure as opm_main.
__global__ __launch_bounds__(256, 2) void zgemm(
    const __hip_bfloat16* __restrict__ Og, const __hip_bfloat16* __restrict__ Wf,
    const float* __restrict__ b_final, float* __restrict__ out) {
  __shared__ __align__(16) char smem[32768];

  const int tid = threadIdx.x;
  const int wave = tid >> 6;
  const int lane = tid & 63;
  const int fr = lane & 15;
  const int fq = lane >> 4;
  const int fqs = fq ^ ((fr >> 1) & 3);
  const int wr = wave >> 1, wc = wave & 1;
  const size_t cell0 = (size_t)blockIdx.x * 128;

  const int srow = tid >> 2;
  const int sk = (((tid & 3) ^ ((tid >> 3) & 3)) * 8);
  const __hip_bfloat16* gO = Og + (cell0 + srow) * 1024 + sk;
  const __hip_bfloat16* gW = Wf + (size_t)srow * 1024 + sk;
  const int ldst = tid * 16;

  const f32x4 fzero = {0.f, 0.f, 0.f, 0.f};
  f32x4 acc[4][4];
#pragma unroll
  for (int i = 0; i < 4; ++i)
#pragma unroll
    for (int j = 0; j < 4; ++j) acc[i][j] = fzero;

  auto stage = [&](int kt, char* base) {
    const int k0 = kt * 32;
    async16(gO + k0, base + ldst);
    async16(gO + (size_t)64 * 1024 + k0, base + 4096 + ldst);
    async16(gW + k0, base + 8192 + ldst);
    async16(gW + (size_t)64 * 1024 + k0, base + 12288 + ldst);
  };
  auto compute = [&](const char* base) {
    const __hip_bfloat16* As = (const __hip_bfloat16*)base;          // O cells
    const __hip_bfloat16* Bs = (const __hip_bfloat16*)(base + 8192); // Wf rows
    short8 af[4], bfr[4];
#pragma unroll
    for (int mt = 0; mt < 4; ++mt)
      af[mt] = *(const short8*)(As + (wr * 64 + mt * 16 + fr) * 32 + fqs * 8);
#pragma unroll
    for (int nt = 0; nt < 4; ++nt)
      bfr[nt] = *(const short8*)(Bs + (wc * 64 + nt * 16 + fr) * 32 + fqs * 8);
#pragma unroll
    for (int mt = 0; mt < 4; ++mt)
#pragma unroll
      for (int nt = 0; nt < 4; ++nt)
        acc[mt][nt] = __builtin_amdgcn_mfma_f32_16x16x32_bf16(
            af[mt], bfr[nt], acc[mt][nt], 0, 0, 0);
  };

  char* buf0 = smem;
  char* buf1 = smem + 16384;
  stage(0, buf0);
  __syncthreads();
  for (int kt = 0; kt < 32; kt += 2) {
    stage(kt + 1, buf1);
    compute(buf0);
    __syncthreads();
    if (kt + 2 < 32) stage(kt + 2, buf0);
    compute(buf1);
    __syncthreads();
  }

  // Z write (+bias). D rows = cells, D cols = z.
#pragma unroll
  for (int nt = 0; nt < 4; ++nt) {
    const int zcol = wc * 64 + nt * 16 + fr;
    const float bz = b_final[zcol];
#pragma unroll
    for (int mt = 0; mt < 4; ++mt) {
      const size_t zrow = cell0 + wr * 64 + mt * 16 + fq * 4;
#pragma unroll
      for (int r = 0; r < 4; ++r)
        out[(zrow + r) * CZ_DIM + zcol] = acc[mt][nt][r] + bz;
    }
  }
}

// Legacy fused kernel (R3) — fallback when workspace can't hold O (302 MB).
__global__ __launch_bounds__(256, 2) void fused_opm(
    const __hip_bfloat16* __restrict__ Abt, const __hip_bfloat16* __restrict__ Bbt,
    const __hip_bfloat16* __restrict__ Wf, const float* __restrict__ b_final,
    float* __restrict__ out) {
  __shared__ __align__(16) char smem[32768];
  const int tid = threadIdx.x;
  const int wave = tid >> 6;
  const int lane = tid & 63;
  const int fr = lane & 15;
  const int fq = lane >> 4;
  const int fqs = fq ^ ((fr >> 1) & 3);
  const int wr = wave >> 1, wc = wave & 1;
  const int bi = blockIdx.y, bj = blockIdx.x;
  const size_t m0 = (size_t)bi * 128;
  const size_t n0 = (size_t)bj * 128;
  const int srow = tid >> 2;
  const int sk = (((tid & 3) ^ ((tid >> 3) & 3)) * 8);
  const __hip_bfloat16* gA = Abt + (m0 + srow) * N_DIM + sk;
  const __hip_bfloat16* gB = Bbt + (n0 + srow) * N_DIM + sk;
  const int ldst = tid * 16;

  const f32x4 fzero = {0.f, 0.f, 0.f, 0.f};
  f32x4 acc[4][4];
#pragma unroll
  for (int i = 0; i < 4; ++i)
#pragma unroll
    for (int j = 0; j < 4; ++j) acc[i][j] = fzero;

  auto stage = [&](int kt, char* base) {
    const int k0 = kt * 32;
    async16(gA + k0, base + ldst);
    async16(gA + (size_t)64 * N_DIM + k0, base + 4096 + ldst);
    async16(gB + k0, base + 8192 + ldst);
    async16(gB + (size_t)64 * N_DIM + k0, base + 12288 + ldst);
  };
  auto compute = [&](const char* base) {
    const __hip_bfloat16* As = (const __hip_bfloat16*)base;
    const __hip_bfloat16* Bs = (const __hip_bfloat16*)(base + 8192);
    short8 af[4], bfr[4];
#pragma unroll
    for (int mt = 0; mt < 4; ++mt)
      af[mt] = *(const short8*)(As + (wr * 64 + mt * 16 + fr) * 32 + fqs * 8);
#pragma unroll
    for (int nt = 0; nt < 4; ++nt)
      bfr[nt] = *(const short8*)(Bs + (wc * 64 + nt * 16 + fr) * 32 + fqs * 8);
#pragma unroll
    for (int mt = 0; mt < 4; ++mt)
#pragma unroll
      for (int nt = 0; nt < 4; ++nt)
        acc[mt][nt] = __builtin_amdgcn_mfma_f32_16x16x32_bf16(
            af[mt], bfr[nt], acc[mt][nt], 0, 0, 0);
  };

  char* buf0 = smem;
  char* buf1 = smem + 16384;
  stage(0, buf0);
  __syncthreads();
  for (int kt = 0; kt < 16; kt += 2) {
    stage(kt + 1, buf1);
    compute(buf0);
    __syncthreads();
    if (kt + 2 < 16) stage(kt + 2, buf0);
    compute(buf1);
    __syncthreads();
  }

  __hip_bfloat16* Oc = (__hip_bfloat16*)smem;  // [16][1024] slot-swizzled
#pragma unroll
  for (int mt = 0; mt < 4; ++mt) {
#pragma unroll
    for (int nt = 0; nt < 4; ++nt) {
      const int orow_b = wr * 64 + mt * 16 + fq * 4;
      const int ocol = wc * 64 + nt * 16 + fr;
#pragma unroll
      for (int r = 0; r < 4; ++r) {
        const int orow = orow_b + r;
        const int cell = ((orow >> 5) << 2) + (ocol >> 5);
        const int kk = ((orow & 31) << 5) + (ocol & 31);
        const int sw = ((((kk >> 3) ^ (cell & 7)) << 3) | (kk & 7));
        Oc[cell * 1024 + sw] = __float2bfloat16(acc[mt][nt][r]);
      }
    }
  }
  __syncthreads();

  f32x4 zacc0 = fzero, zacc1 = fzero;
  const int zt0 = wave * 2;
  const int xr = fr & 7;
  for (int kk = 0; kk < 32; ++kk) {
    const int slot = kk * 4 + fq;
    const short8 oa = *(const short8*)(Oc + fr * 1024 + ((slot ^ xr) << 3));
    const short8 wb0 =
        *(const short8*)(Wf + (size_t)((zt0 + 0) * 16 + fr) * 1024 + kk * 32 + fq * 8);
    const short8 wb1 =
        *(const short8*)(Wf + (size_t)((zt0 + 1) * 16 + fr) * 1024 + kk * 32 + fq * 8);
    zacc0 = __builtin_amdgcn_mfma_f32_16x16x32_bf16(oa, wb0, zacc0, 0, 0, 0);
    zacc1 = __builtin_amdgcn_mfma_f32_16x16x32_bf16(oa, wb1, zacc1, 0, 0, 0);
  }

  const int i0 = bi * 4, j0 = bj * 4;
#pragma unroll
  for (int t = 0; t < 2; ++t) {
    const int zcol = (zt0 + t) * 16 + fr;
    const float bz = b_final[zcol];
    const f32x4 za = t ? zacc1 : zacc0;
#pragma unroll
    for (int r = 0; r < 4; ++r) {
      const int cell = fq * 4 + r;
      const int li = cell >> 2, lj = cell & 3;
      out[((size_t)(i0 + li) * S_DIM + (j0 + lj)) * CZ_DIM + zcol] = za[r] + bz;
    }
  }
}

extern "C" void kernel_launch(void* const* d_in, const int* in_sizes, int n_in,
                              void* d_out, int out_size, void* d_ws, size_t ws_size,
                              hipStream_t stream) {
  const float* m_si = (const float*)d_in[0];
  const float* ln_g = (const float*)d_in[1];
  const float* ln_b = (const float*)d_in[2];
  const float* w_ab = (const float*)d_in[3];
  const float* w_final = (const float*)d_in[4];
  const float* b_final = (const float*)d_in[5];
  float* out = (float*)d_out;

  char* ws = (char*)d_ws;
  __hip_bfloat16* Abt = (__hip_bfloat16*)ws;                                // 12.58 MB
  __hip_bfloat16* Bbt = (__hip_bfloat16*)(ws + (size_t)MROWS * N_DIM * 2);  // 12.58 MB
  __hip_bfloat16* Wf = (__hip_bfloat16*)(ws + (size_t)MROWS * N_DIM * 4);   // 256 KB
  __hip_bfloat16* Og =
      (__hip_bfloat16*)(ws + (size_t)MROWS * N_DIM * 4 + 262144);           // 302 MB

  const size_t need =
      (size_t)MROWS * N_DIM * 4 + 262144 + (size_t)NCELL * 1024 * 2;

  prep_kernel<<<dim3(2, S_DIM), 256, 0, stream>>>(m_si, ln_g, ln_b, w_ab, Abt, Bbt);
  conv_wf<<<dim3((CZ_DIM * 1024) / 256), 256, 0, stream>>>(w_final, Wf);

  if (ws_size >= need) {
    opm_main<<<dim3(96, 96), 256, 0, stream>>>(Abt, Bbt, Og);
    zgemm<<<dim3(NCELL / 128), 256, 0, stream>>>(Og, Wf, b_final, out);
  } else {
    fused_opm<<<dim3(96, 96), 256, 0, stream>>>(Abt, Bbt, Wf, b_final, out);
  }
}

// Round 7
// 376.992 us; speedup vs baseline: 1.3672x; 1.2426x over previous
//
#include <hip/hip_runtime.h>
#include <hip/hip_bf16.h>

typedef __attribute__((ext_vector_type(8))) short short8;
typedef __attribute__((ext_vector_type(4))) float f32x4;

#define S_DIM 384
#define N_DIM 512
#define C_DIM 32
#define CZ_DIM 128
#define MROWS (S_DIM * C_DIM)   /* 12288 */
#define NCELL (S_DIM * S_DIM)   /* 147456 */

__device__ __forceinline__ void async16(const void* g, void* l) {
  __builtin_amdgcn_global_load_lds(
      (const __attribute__((address_space(1))) void*)g,
      (__attribute__((address_space(3))) void*)l, 16, 0, 0);
}

// Kernel 1: LayerNorm + w_ab projection.
__global__ __launch_bounds__(256) void prep_kernel(
    const float* __restrict__ m_si, const float* __restrict__ ln_g,
    const float* __restrict__ ln_b, const float* __restrict__ w_ab,
    __hip_bfloat16* __restrict__ Abt, __hip_bfloat16* __restrict__ Bbt) {
  const int n = blockIdx.x * 256 + threadIdx.x;  // 0..511
  const int s = blockIdx.y;                      // 0..383
  const float* x = m_si + ((size_t)s * N_DIM + n) * C_DIM;

  float v[C_DIM];
#pragma unroll
  for (int i = 0; i < 8; ++i) {
    float4 t = ((const float4*)x)[i];
    v[4 * i + 0] = t.x; v[4 * i + 1] = t.y;
    v[4 * i + 2] = t.z; v[4 * i + 3] = t.w;
  }
  float sum = 0.f;
#pragma unroll
  for (int c = 0; c < C_DIM; ++c) sum += v[c];
  const float mu = sum * (1.f / 32.f);
  float sq = 0.f;
#pragma unroll
  for (int c = 0; c < C_DIM; ++c) { float d = v[c] - mu; sq += d * d; }
  const float rstd = rsqrtf(sq * (1.f / 32.f) + 1e-5f);

  float mn[C_DIM];
#pragma unroll
  for (int c = 0; c < C_DIM; ++c)
    mn[c] = (v[c] - mu) * rstd * ln_g[c] + ln_b[c];

#pragma unroll 4
  for (int d = 0; d < 32; ++d) {
    float aA = 0.f, aB = 0.f;
#pragma unroll
    for (int c = 0; c < C_DIM; ++c) {
      aA += mn[c] * w_ab[d * C_DIM + c];
      aB += mn[c] * w_ab[(d + 32) * C_DIM + c];
    }
    Abt[((size_t)(s * 32 + d)) * N_DIM + n] = __float2bfloat16(aA * (1.f / 512.f));
    Bbt[((size_t)(s * 32 + d)) * N_DIM + n] = __float2bfloat16(aB);
  }
}

// Kernel 2: w_final fp32 -> bf16 (128 x 1024)
__global__ __launch_bounds__(256) void conv_wf(const float* __restrict__ w_final,
                                               __hip_bfloat16* __restrict__ Wf) {
  const int i = blockIdx.x * 256 + threadIdx.x;
  Wf[i] = __float2bfloat16(w_final[i]);
}

// Kernel 3a (split path): main outer-product GEMM only (one i-slab).
// 128x128 tile, K=512, 4 waves 2x2, R3's proven dbuf loop + k-slot swizzle.
// O-store: acc -> Oc LDS (slot-swizzled, proven phase-1 code) -> de-swizzled
// coalesced b128 global stores. Og layout: linear [cellLocal][c*32+d] bf16.
__global__ __launch_bounds__(256, 2) void opm_main(
    const __hip_bfloat16* __restrict__ Abt, const __hip_bfloat16* __restrict__ Bbt,
    __hip_bfloat16* __restrict__ Og, int bi0) {
  __shared__ __align__(16) char smem[32768];

  const int tid = threadIdx.x;
  const int wave = tid >> 6;
  const int lane = tid & 63;
  const int fr = lane & 15;
  const int fq = lane >> 4;
  const int fqs = fq ^ ((fr >> 1) & 3);  // swizzled physical k-slot
  const int wr = wave >> 1, wc = wave & 1;
  const int biL = blockIdx.y;            // slab-local block row
  const int bj = blockIdx.x;

  const size_t m0 = (size_t)(bi0 + biL) * 128;
  const size_t n0 = (size_t)bj * 128;

  const int srow = tid >> 2;
  const int sk = (((tid & 3) ^ ((tid >> 3) & 3)) * 8);  // pre-swizzled k offset
  const __hip_bfloat16* gA = Abt + (m0 + srow) * N_DIM + sk;
  const __hip_bfloat16* gB = Bbt + (n0 + srow) * N_DIM + sk;
  const int ldst = tid * 16;

  const f32x4 fzero = {0.f, 0.f, 0.f, 0.f};
  f32x4 acc[4][4];
#pragma unroll
  for (int i = 0; i < 4; ++i)
#pragma unroll
    for (int j = 0; j < 4; ++j) acc[i][j] = fzero;

  auto stage = [&](int kt, char* base) {
    const int k0 = kt * 32;
    async16(gA + k0, base + ldst);
    async16(gA + (size_t)64 * N_DIM + k0, base + 4096 + ldst);
    async16(gB + k0, base + 8192 + ldst);
    async16(gB + (size_t)64 * N_DIM + k0, base + 12288 + ldst);
  };
  auto compute = [&](const char* base) {
    const __hip_bfloat16* As = (const __hip_bfloat16*)base;
    const __hip_bfloat16* Bs = (const __hip_bfloat16*)(base + 8192);
    short8 af[4], bfr[4];
#pragma unroll
    for (int mt = 0; mt < 4; ++mt)
      af[mt] = *(const short8*)(As + (wr * 64 + mt * 16 + fr) * 32 + fqs * 8);
#pragma unroll
    for (int nt = 0; nt < 4; ++nt)
      bfr[nt] = *(const short8*)(Bs + (wc * 64 + nt * 16 + fr) * 32 + fqs * 8);
#pragma unroll
    for (int mt = 0; mt < 4; ++mt)
#pragma unroll
      for (int nt = 0; nt < 4; ++nt)
        acc[mt][nt] = __builtin_amdgcn_mfma_f32_16x16x32_bf16(
            af[mt], bfr[nt], acc[mt][nt], 0, 0, 0);
  };

  char* buf0 = smem;
  char* buf1 = smem + 16384;
  stage(0, buf0);
  __syncthreads();
  for (int kt = 0; kt < 16; kt += 2) {
    stage(kt + 1, buf1);
    compute(buf0);
    __syncthreads();
    if (kt + 2 < 16) stage(kt + 2, buf0);
    compute(buf1);
    __syncthreads();
  }

  // Phase 1: acc -> Oc LDS bf16, slot-swizzled (32 KB = 16 cells x 1024).
  __hip_bfloat16* Oc = (__hip_bfloat16*)smem;
#pragma unroll
  for (int mt = 0; mt < 4; ++mt) {
#pragma unroll
    for (int nt = 0; nt < 4; ++nt) {
      const int orow_b = wr * 64 + mt * 16 + fq * 4;
      const int ocol = wc * 64 + nt * 16 + fr;  // C/D map: col=lane&15
#pragma unroll
      for (int r = 0; r < 4; ++r) {             // row=(lane>>4)*4+reg
        const int orow = orow_b + r;
        const int cell = ((orow >> 5) << 2) + (ocol >> 5);  // li*4+lj
        const int kk = ((orow & 31) << 5) + (ocol & 31);    // c*32+d
        const int sw = ((((kk >> 3) ^ (cell & 7)) << 3) | (kk & 7));
        Oc[cell * 1024 + sw] = __float2bfloat16(acc[mt][nt][r]);
      }
    }
  }
  __syncthreads();

  // Phase 2: de-swizzled, coalesced b128 O-store. 8 x 16B per thread.
  const __hip_bfloat16* OcR = (const __hip_bfloat16*)smem;
#pragma unroll
  for (int j = 0; j < 8; ++j) {
    const int lc = j * 256 + tid;   // logical 16B-chunk index, 0..2047
    const int cellL = lc >> 7;      // 0..15
    const int ch = lc & 127;        // chunk within cell (kk>>3)
    const int phys = (ch & ~7) | ((ch & 7) ^ (cellL & 7));
    const short8 val = *(const short8*)(OcR + cellL * 1024 + phys * 8);
    const int li = cellL >> 2, lj = cellL & 3;
    __hip_bfloat16* dst =
        Og + ((size_t)((biL * 4 + li) * S_DIM + (bj * 4 + lj))) * 1024 + ch * 8;
    *(short8*)dst = val;
  }
}

// Kernel 3b (split path): Z[cells][128] = O[cells][1024] @ Wf[128][1024]^T + b.
// 128-cell x 128-z tile per block (4 waves 2x2); K=1024 in 32 dbuf steps.
__global__ __launch_bounds__(256, 2) void zgemm(
    const __hip_bfloat16* __restrict__ Og, const __hip_bfloat16* __restrict__ Wf,
    const float* __restrict__ b_final, float* __restrict__ out) {
  __shared__ __align__(16) char smem[32768];

  const int tid = threadIdx.x;
  const int wave = tid >> 6;
  const int lane = tid & 63;
  const int fr = lane & 15;
  const int fq = lane >> 4;
  const int fqs = fq ^ ((fr >> 1) & 3);
  const int wr = wave >> 1, wc = wave & 1;
  const size_t cell0 = (size_t)blockIdx.x * 128;

  const int srow = tid >> 2;
  const int sk = (((tid & 3) ^ ((tid >> 3) & 3)) * 8);
  const __hip_bfloat16* gO = Og + (cell0 + srow) * 1024 + sk;
  const __hip_bfloat16* gW = Wf + (size_t)srow * 1024 + sk;
  const int ldst = tid * 16;

  const f32x4 fzero = {0.f, 0.f, 0.f, 0.f};
  f32x4 acc[4][4];
#pragma unroll
  for (int i = 0; i < 4; ++i)
#pragma unroll
    for (int j = 0; j < 4; ++j) acc[i][j] = fzero;

  auto stage = [&](int kt, char* base) {
    const int k0 = kt * 32;
    async16(gO + k0, base + ldst);
    async16(gO + (size_t)64 * 1024 + k0, base + 4096 + ldst);
    async16(gW + k0, base + 8192 + ldst);
    async16(gW + (size_t)64 * 1024 + k0, base + 12288 + ldst);
  };
  auto compute = [&](const char* base) {
    const __hip_bfloat16* As = (const __hip_bfloat16*)base;          // O cells
    const __hip_bfloat16* Bs = (const __hip_bfloat16*)(base + 8192); // Wf rows
    short8 af[4], bfr[4];
#pragma unroll
    for (int mt = 0; mt < 4; ++mt)
      af[mt] = *(const short8*)(As + (wr * 64 + mt * 16 + fr) * 32 + fqs * 8);
#pragma unroll
    for (int nt = 0; nt < 4; ++nt)
      bfr[nt] = *(const short8*)(Bs + (wc * 64 + nt * 16 + fr) * 32 + fqs * 8);
#pragma unroll
    for (int mt = 0; mt < 4; ++mt)
#pragma unroll
      for (int nt = 0; nt < 4; ++nt)
        acc[mt][nt] = __builtin_amdgcn_mfma_f32_16x16x32_bf16(
            af[mt], bfr[nt], acc[mt][nt], 0, 0, 0);
  };

  char* buf0 = smem;
  char* buf1 = smem + 16384;
  stage(0, buf0);
  __syncthreads();
  for (int kt = 0; kt < 32; kt += 2) {
    stage(kt + 1, buf1);
    compute(buf0);
    __syncthreads();
    if (kt + 2 < 32) stage(kt + 2, buf0);
    compute(buf1);
    __syncthreads();
  }

  // Z write (+bias). D rows = cells, D cols = z.
#pragma unroll
  for (int nt = 0; nt < 4; ++nt) {
    const int zcol = wc * 64 + nt * 16 + fr;
    const float bz = b_final[zcol];
#pragma unroll
    for (int mt = 0; mt < 4; ++mt) {
      const size_t zrow = cell0 + wr * 64 + mt * 16 + fq * 4;
#pragma unroll
      for (int r = 0; r < 4; ++r)
        out[(zrow + r) * CZ_DIM + zcol] = acc[mt][nt][r] + bz;
    }
  }
}

// Legacy fused kernel (R3) — fallback when workspace can't hold even one O slab.
__global__ __launch_bounds__(256, 2) void fused_opm(
    const __hip_bfloat16* __restrict__ Abt, const __hip_bfloat16* __restrict__ Bbt,
    const __hip_bfloat16* __restrict__ Wf, const float* __restrict__ b_final,
    float* __restrict__ out) {
  __shared__ __align__(16) char smem[32768];
  const int tid = threadIdx.x;
  const int wave = tid >> 6;
  const int lane = tid & 63;
  const int fr = lane & 15;
  const int fq = lane >> 4;
  const int fqs = fq ^ ((fr >> 1) & 3);
  const int wr = wave >> 1, wc = wave & 1;
  const int bi = blockIdx.y, bj = blockIdx.x;
  const size_t m0 = (size_t)bi * 128;
  const size_t n0 = (size_t)bj * 128;
  const int srow = tid >> 2;
  const int sk = (((tid & 3) ^ ((tid >> 3) & 3)) * 8);
  const __hip_bfloat16* gA = Abt + (m0 + srow) * N_DIM + sk;
  const __hip_bfloat16* gB = Bbt + (n0 + srow) * N_DIM + sk;
  const int ldst = tid * 16;

  const f32x4 fzero = {0.f, 0.f, 0.f, 0.f};
  f32x4 acc[4][4];
#pragma unroll
  for (int i = 0; i < 4; ++i)
#pragma unroll
    for (int j = 0; j < 4; ++j) acc[i][j] = fzero;

  auto stage = [&](int kt, char* base) {
    const int k0 = kt * 32;
    async16(gA + k0, base + ldst);
    async16(gA + (size_t)64 * N_DIM + k0, base + 4096 + ldst);
    async16(gB + k0, base + 8192 + ldst);
    async16(gB + (size_t)64 * N_DIM + k0, base + 12288 + ldst);
  };
  auto compute = [&](const char* base) {
    const __hip_bfloat16* As = (const __hip_bfloat16*)base;
    const __hip_bfloat16* Bs = (const __hip_bfloat16*)(base + 8192);
    short8 af[4], bfr[4];
#pragma unroll
    for (int mt = 0; mt < 4; ++mt)
      af[mt] = *(const short8*)(As + (wr * 64 + mt * 16 + fr) * 32 + fqs * 8);
#pragma unroll
    for (int nt = 0; nt < 4; ++nt)
      bfr[nt] = *(const short8*)(Bs + (wc * 64 + nt * 16 + fr) * 32 + fqs * 8);
#pragma unroll
    for (int mt = 0; mt < 4; ++mt)
#pragma unroll
      for (int nt = 0; nt < 4; ++nt)
        acc[mt][nt] = __builtin_amdgcn_mfma_f32_16x16x32_bf16(
            af[mt], bfr[nt], acc[mt][nt], 0, 0, 0);
  };

  char* buf0 = smem;
  char* buf1 = smem + 16384;
  stage(0, buf0);
  __syncthreads();
  for (int kt = 0; kt < 16; kt += 2) {
    stage(kt + 1, buf1);
    compute(buf0);
    __syncthreads();
    if (kt + 2 < 16) stage(kt + 2, buf0);
    compute(buf1);
    __syncthreads();
  }

  __hip_bfloat16* Oc = (__hip_bfloat16*)smem;  // [16][1024] slot-swizzled
#pragma unroll
  for (int mt = 0; mt < 4; ++mt) {
#pragma unroll
    for (int nt = 0; nt < 4; ++nt) {
      const int orow_b = wr * 64 + mt * 16 + fq * 4;
      const int ocol = wc * 64 + nt * 16 + fr;
#pragma unroll
      for (int r = 0; r < 4; ++r) {
        const int orow = orow_b + r;
        const int cell = ((orow >> 5) << 2) + (ocol >> 5);
        const int kk = ((orow & 31) << 5) + (ocol & 31);
        const int sw = ((((kk >> 3) ^ (cell & 7)) << 3) | (kk & 7));
        Oc[cell * 1024 + sw] = __float2bfloat16(acc[mt][nt][r]);
      }
    }
  }
  __syncthreads();

  f32x4 zacc0 = fzero, zacc1 = fzero;
  const int zt0 = wave * 2;
  const int xr = fr & 7;
  for (int kk = 0; kk < 32; ++kk) {
    const int slot = kk * 4 + fq;
    const short8 oa = *(const short8*)(Oc + fr * 1024 + ((slot ^ xr) << 3));
    const short8 wb0 =
        *(const short8*)(Wf + (size_t)((zt0 + 0) * 16 + fr) * 1024 + kk * 32 + fq * 8);
    const short8 wb1 =
        *(const short8*)(Wf + (size_t)((zt0 + 1) * 16 + fr) * 1024 + kk * 32 + fq * 8);
    zacc0 = __builtin_amdgcn_mfma_f32_16x16x32_bf16(oa, wb0, zacc0, 0, 0, 0);
    zacc1 = __builtin_amdgcn_mfma_f32_16x16x32_bf16(oa, wb1, zacc1, 0, 0, 0);
  }

  const int i0 = bi * 4, j0 = bj * 4;
#pragma unroll
  for (int t = 0; t < 2; ++t) {
    const int zcol = (zt0 + t) * 16 + fr;
    const float bz = b_final[zcol];
    const f32x4 za = t ? zacc1 : zacc0;
#pragma unroll
    for (int r = 0; r < 4; ++r) {
      const int cell = fq * 4 + r;
      const int li = cell >> 2, lj = cell & 3;
      out[((size_t)(i0 + li) * S_DIM + (j0 + lj)) * CZ_DIM + zcol] = za[r] + bz;
    }
  }
}

extern "C" void kernel_launch(void* const* d_in, const int* in_sizes, int n_in,
                              void* d_out, int out_size, void* d_ws, size_t ws_size,
                              hipStream_t stream) {
  const float* m_si = (const float*)d_in[0];
  const float* ln_g = (const float*)d_in[1];
  const float* ln_b = (const float*)d_in[2];
  const float* w_ab = (const float*)d_in[3];
  const float* w_final = (const float*)d_in[4];
  const float* b_final = (const float*)d_in[5];
  float* out = (float*)d_out;

  char* ws = (char*)d_ws;
  __hip_bfloat16* Abt = (__hip_bfloat16*)ws;                                // 12.58 MB
  __hip_bfloat16* Bbt = (__hip_bfloat16*)(ws + (size_t)MROWS * N_DIM * 2);  // 12.58 MB
  __hip_bfloat16* Wf = (__hip_bfloat16*)(ws + (size_t)MROWS * N_DIM * 4);   // 256 KB
  const size_t base = (size_t)MROWS * N_DIM * 4 + 262144;
  __hip_bfloat16* Og = (__hip_bfloat16*)(ws + base);

  prep_kernel<<<dim3(2, S_DIM), 256, 0, stream>>>(m_si, ln_g, ln_b, w_ab, Abt, Bbt);
  conv_wf<<<dim3((CZ_DIM * 1024) / 256), 256, 0, stream>>>(w_final, Wf);

  // Pick the largest O slab (fewest slabs) fitting the workspace.
  static const int cands[] = {1, 2, 3, 4, 6, 8, 12, 16, 24, 32};
  int nslab = 0;
  for (int c : cands) {
    if (base + ((size_t)NCELL / c) * 1024 * 2 <= ws_size) { nslab = c; break; }
  }

  if (nslab) {
    const int biPer = 96 / nslab;                    // block-rows per slab
    const int cellsPer = NCELL / nslab;              // cells per slab
    for (int s = 0; s < nslab; ++s) {
      opm_main<<<dim3(96, biPer), 256, 0, stream>>>(Abt, Bbt, Og, s * biPer);
      zgemm<<<dim3(cellsPer / 128), 256, 0, stream>>>(
          Og, Wf, b_final, out + (size_t)s * cellsPer * CZ_DIM);
    }
  } else {
    fused_opm<<<dim3(96, 96), 256, 0, stream>>>(Abt, Bbt, Wf, b_final, out);
  }
}

// Round 9
// 367.447 us; speedup vs baseline: 1.4027x; 1.0260x over previous
//
#include <hip/hip_runtime.h>
#include <hip/hip_bf16.h>

typedef __attribute__((ext_vector_type(8))) short short8;
typedef __attribute__((ext_vector_type(4))) float f32x4;

#define S_DIM 384
#define N_DIM 512
#define C_DIM 32
#define CZ_DIM 128
#define MROWS (S_DIM * C_DIM)   /* 12288 */
#define NCELL (S_DIM * S_DIM)   /* 147456 */

__device__ __forceinline__ void async16(const void* g, void* l) {
  __builtin_amdgcn_global_load_lds(
      (const __attribute__((address_space(1))) void*)g,
      (__attribute__((address_space(3))) void*)l, 16, 0, 0);
}

// Kernel 1: LayerNorm + w_ab projection.
__global__ __launch_bounds__(256) void prep_kernel(
    const float* __restrict__ m_si, const float* __restrict__ ln_g,
    const float* __restrict__ ln_b, const float* __restrict__ w_ab,
    __hip_bfloat16* __restrict__ Abt, __hip_bfloat16* __restrict__ Bbt) {
  const int n = blockIdx.x * 256 + threadIdx.x;  // 0..511
  const int s = blockIdx.y;                      // 0..383
  const float* x = m_si + ((size_t)s * N_DIM + n) * C_DIM;

  float v[C_DIM];
#pragma unroll
  for (int i = 0; i < 8; ++i) {
    float4 t = ((const float4*)x)[i];
    v[4 * i + 0] = t.x; v[4 * i + 1] = t.y;
    v[4 * i + 2] = t.z; v[4 * i + 3] = t.w;
  }
  float sum = 0.f;
#pragma unroll
  for (int c = 0; c < C_DIM; ++c) sum += v[c];
  const float mu = sum * (1.f / 32.f);
  float sq = 0.f;
#pragma unroll
  for (int c = 0; c < C_DIM; ++c) { float d = v[c] - mu; sq += d * d; }
  const float rstd = rsqrtf(sq * (1.f / 32.f) + 1e-5f);

  float mn[C_DIM];
#pragma unroll
  for (int c = 0; c < C_DIM; ++c)
    mn[c] = (v[c] - mu) * rstd * ln_g[c] + ln_b[c];

#pragma unroll 4
  for (int d = 0; d < 32; ++d) {
    float aA = 0.f, aB = 0.f;
#pragma unroll
    for (int c = 0; c < C_DIM; ++c) {
      aA += mn[c] * w_ab[d * C_DIM + c];
      aB += mn[c] * w_ab[(d + 32) * C_DIM + c];
    }
    Abt[((size_t)(s * 32 + d)) * N_DIM + n] = __float2bfloat16(aA * (1.f / 512.f));
    Bbt[((size_t)(s * 32 + d)) * N_DIM + n] = __float2bfloat16(aB);
  }
}

// Kernel 2: w_final fp32 -> bf16 (128 x 1024)
__global__ __launch_bounds__(256) void conv_wf(const float* __restrict__ w_final,
                                               __hip_bfloat16* __restrict__ Wf) {
  const int i = blockIdx.x * 256 + threadIdx.x;
  Wf[i] = __float2bfloat16(w_final[i]);
}

// Kernel 3a (split path): main outer-product GEMM only (one i-slab).
// 128x128 tile, K=512, 4 waves 2x2, dbuf loop + k-slot swizzle.
// R8: XCD bj-BAND remap. Dispatch round-robins flat ids over 8 XCDs
// (xcd = f%8); XCD x owns bj in [12x, 12x+12) and sweeps biL outer /
// bj inner. Per-XCD L2 working set: 12 B-panels (1.5 MB, resident all
// dispatch) + ~13 active A-panels (1.7 MB) -> L3->L2 traffic ~19x lower
// than row-major order. Bijective for any gridDim.y (96*biPer % 8 == 0).
__global__ __launch_bounds__(256, 2) void opm_main(
    const __hip_bfloat16* __restrict__ Abt, const __hip_bfloat16* __restrict__ Bbt,
    __hip_bfloat16* __restrict__ Og, int bi0) {
  __shared__ __align__(16) char smem[32768];

  const int tid = threadIdx.x;
  const int wave = tid >> 6;
  const int lane = tid & 63;
  const int fr = lane & 15;
  const int fq = lane >> 4;
  const int fqs = fq ^ ((fr >> 1) & 3);  // swizzled physical k-slot
  const int wr = wave >> 1, wc = wave & 1;

  // XCD bj-band remap.
  const int f = blockIdx.y * 96 + blockIdx.x;
  const int xcd = f & 7;
  const int i_ = f >> 3;
  const int bj = xcd * 12 + (i_ % 12);   // 12-column band per XCD
  const int biL = i_ / 12;               // slab-local block row

  const size_t m0 = (size_t)(bi0 + biL) * 128;
  const size_t n0 = (size_t)bj * 128;

  const int srow = tid >> 2;
  const int sk = (((tid & 3) ^ ((tid >> 3) & 3)) * 8);  // pre-swizzled k offset
  const __hip_bfloat16* gA = Abt + (m0 + srow) * N_DIM + sk;
  const __hip_bfloat16* gB = Bbt + (n0 + srow) * N_DIM + sk;
  const int ldst = tid * 16;

  const f32x4 fzero = {0.f, 0.f, 0.f, 0.f};
  f32x4 acc[4][4];
#pragma unroll
  for (int i = 0; i < 4; ++i)
#pragma unroll
    for (int j = 0; j < 4; ++j) acc[i][j] = fzero;

  auto stage = [&](int kt, char* base) {
    const int k0 = kt * 32;
    async16(gA + k0, base + ldst);
    async16(gA + (size_t)64 * N_DIM + k0, base + 4096 + ldst);
    async16(gB + k0, base + 8192 + ldst);
    async16(gB + (size_t)64 * N_DIM + k0, base + 12288 + ldst);
  };
  auto compute = [&](const char* base) {
    const __hip_bfloat16* As = (const __hip_bfloat16*)base;
    const __hip_bfloat16* Bs = (const __hip_bfloat16*)(base + 8192);
    short8 af[4], bfr[4];
#pragma unroll
    for (int mt = 0; mt < 4; ++mt)
      af[mt] = *(const short8*)(As + (wr * 64 + mt * 16 + fr) * 32 + fqs * 8);
#pragma unroll
    for (int nt = 0; nt < 4; ++nt)
      bfr[nt] = *(const short8*)(Bs + (wc * 64 + nt * 16 + fr) * 32 + fqs * 8);
#pragma unroll
    for (int mt = 0; mt < 4; ++mt)
#pragma unroll
      for (int nt = 0; nt < 4; ++nt)
        acc[mt][nt] = __builtin_amdgcn_mfma_f32_16x16x32_bf16(
            af[mt], bfr[nt], acc[mt][nt], 0, 0, 0);
  };

  char* buf0 = smem;
  char* buf1 = smem + 16384;
  stage(0, buf0);
  __syncthreads();
  for (int kt = 0; kt < 16; kt += 2) {
    stage(kt + 1, buf1);
    compute(buf0);
    __syncthreads();
    if (kt + 2 < 16) stage(kt + 2, buf0);
    compute(buf1);
    __syncthreads();
  }

  // Phase 1: acc -> Oc LDS bf16, slot-swizzled (32 KB = 16 cells x 1024).
  __hip_bfloat16* Oc = (__hip_bfloat16*)smem;
#pragma unroll
  for (int mt = 0; mt < 4; ++mt) {
#pragma unroll
    for (int nt = 0; nt < 4; ++nt) {
      const int orow_b = wr * 64 + mt * 16 + fq * 4;
      const int ocol = wc * 64 + nt * 16 + fr;  // C/D map: col=lane&15
#pragma unroll
      for (int r = 0; r < 4; ++r) {             // row=(lane>>4)*4+reg
        const int orow = orow_b + r;
        const int cell = ((orow >> 5) << 2) + (ocol >> 5);  // li*4+lj
        const int kk = ((orow & 31) << 5) + (ocol & 31);    // c*32+d
        const int sw = ((((kk >> 3) ^ (cell & 7)) << 3) | (kk & 7));
        Oc[cell * 1024 + sw] = __float2bfloat16(acc[mt][nt][r]);
      }
    }
  }
  __syncthreads();

  // Phase 2: de-swizzled, coalesced b128 O-store. 8 x 16B per thread.
  const __hip_bfloat16* OcR = (const __hip_bfloat16*)smem;
#pragma unroll
  for (int j = 0; j < 8; ++j) {
    const int lc = j * 256 + tid;   // logical 16B-chunk index, 0..2047
    const int cellL = lc >> 7;      // 0..15
    const int ch = lc & 127;        // chunk within cell (kk>>3)
    const int phys = (ch & ~7) | ((ch & 7) ^ (cellL & 7));
    const short8 val = *(const short8*)(OcR + cellL * 1024 + phys * 8);
    const int li = cellL >> 2, lj = cellL & 3;
    __hip_bfloat16* dst =
        Og + ((size_t)((biL * 4 + li) * S_DIM + (bj * 4 + lj))) * 1024 + ch * 8;
    *(short8*)dst = val;
  }
}

// Kernel 3b (split path): Z[cells][128] = O[cells][1024] @ Wf[128][1024]^T + b.
// 128-cell x 128-z tile per block (4 waves 2x2); K=1024 in 32 dbuf steps.
__global__ __launch_bounds__(256, 2) void zgemm(
    const __hip_bfloat16* __restrict__ Og, const __hip_bfloat16* __restrict__ Wf,
    const float* __restrict__ b_final, float* __restrict__ out) {
  __shared__ __align__(16) char smem[32768];

  const int tid = threadIdx.x;
  const int wave = tid >> 6;
  const int lane = tid & 63;
  const int fr = lane & 15;
  const int fq = lane >> 4;
  const int fqs = fq ^ ((fr >> 1) & 3);
  const int wr = wave >> 1, wc = wave & 1;
  const size_t cell0 = (size_t)blockIdx.x * 128;

  const int srow = tid >> 2;
  const int sk = (((tid & 3) ^ ((tid >> 3) & 3)) * 8);
  const __hip_bfloat16* gO = Og + (cell0 + srow) * 1024 + sk;
  const __hip_bfloat16* gW = Wf + (size_t)srow * 1024 + sk;
  const int ldst = tid * 16;

  const f32x4 fzero = {0.f, 0.f, 0.f, 0.f};
  f32x4 acc[4][4];
#pragma unroll
  for (int i = 0; i < 4; ++i)
#pragma unroll
    for (int j = 0; j < 4; ++j) acc[i][j] = fzero;

  auto stage = [&](int kt, char* base) {
    const int k0 = kt * 32;
    async16(gO + k0, base + ldst);
    async16(gO + (size_t)64 * 1024 + k0, base + 4096 + ldst);
    async16(gW + k0, base + 8192 + ldst);
    async16(gW + (size_t)64 * 1024 + k0, base + 12288 + ldst);
  };
  auto compute = [&](const char* base) {
    const __hip_bfloat16* As = (const __hip_bfloat16*)base;          // O cells
    const __hip_bfloat16* Bs = (const __hip_bfloat16*)(base + 8192); // Wf rows
    short8 af[4], bfr[4];
#pragma unroll
    for (int mt = 0; mt < 4; ++mt)
      af[mt] = *(const short8*)(As + (wr * 64 + mt * 16 + fr) * 32 + fqs * 8);
#pragma unroll
    for (int nt = 0; nt < 4; ++nt)
      bfr[nt] = *(const short8*)(Bs + (wc * 64 + nt * 16 + fr) * 32 + fqs * 8);
#pragma unroll
    for (int mt = 0; mt < 4; ++mt)
#pragma unroll
      for (int nt = 0; nt < 4; ++nt)
        acc[mt][nt] = __builtin_amdgcn_mfma_f32_16x16x32_bf16(
            af[mt], bfr[nt], acc[mt][nt], 0, 0, 0);
  };

  char* buf0 = smem;
  char* buf1 = smem + 16384;
  stage(0, buf0);
  __syncthreads();
  for (int kt = 0; kt < 32; kt += 2) {
    stage(kt + 1, buf1);
    compute(buf0);
    __syncthreads();
    if (kt + 2 < 32) stage(kt + 2, buf0);
    compute(buf1);
    __syncthreads();
  }

  // Z write (+bias). D rows = cells, D cols = z.
#pragma unroll
  for (int nt = 0; nt < 4; ++nt) {
    const int zcol = wc * 64 + nt * 16 + fr;
    const float bz = b_final[zcol];
#pragma unroll
    for (int mt = 0; mt < 4; ++mt) {
      const size_t zrow = cell0 + wr * 64 + mt * 16 + fq * 4;
#pragma unroll
      for (int r = 0; r < 4; ++r)
        out[(zrow + r) * CZ_DIM + zcol] = acc[mt][nt][r] + bz;
    }
  }
}

// Legacy fused kernel (R3) — fallback when workspace can't hold even one O slab.
__global__ __launch_bounds__(256, 2) void fused_opm(
    const __hip_bfloat16* __restrict__ Abt, const __hip_bfloat16* __restrict__ Bbt,
    const __hip_bfloat16* __restrict__ Wf, const float* __restrict__ b_final,
    float* __restrict__ out) {
  __shared__ __align__(16) char smem[32768];
  const int tid = threadIdx.x;
  const int wave = tid >> 6;
  const int lane = tid & 63;
  const int fr = lane & 15;
  const int fq = lane >> 4;
  const int fqs = fq ^ ((fr >> 1) & 3);
  const int wr = wave >> 1, wc = wave & 1;
  const int bi = blockIdx.y, bj = blockIdx.x;
  const size_t m0 = (size_t)bi * 128;
  const size_t n0 = (size_t)bj * 128;
  const int srow = tid >> 2;
  const int sk = (((tid & 3) ^ ((tid >> 3) & 3)) * 8);
  const __hip_bfloat16* gA = Abt + (m0 + srow) * N_DIM + sk;
  const __hip_bfloat16* gB = Bbt + (n0 + srow) * N_DIM + sk;
  const int ldst = tid * 16;

  const f32x4 fzero = {0.f, 0.f, 0.f, 0.f};
  f32x4 acc[4][4];
#pragma unroll
  for (int i = 0; i < 4; ++i)
#pragma unroll
    for (int j = 0; j < 4; ++j) acc[i][j] = fzero;

  auto stage = [&](int kt, char* base) {
    const int k0 = kt * 32;
    async16(gA + k0, base + ldst);
    async16(gA + (size_t)64 * N_DIM + k0, base + 4096 + ldst);
    async16(gB + k0, base + 8192 + ldst);
    async16(gB + (size_t)64 * N_DIM + k0, base + 12288 + ldst);
  };
  auto compute = [&](const char* base) {
    const __hip_bfloat16* As = (const __hip_bfloat16*)base;
    const __hip_bfloat16* Bs = (const __hip_bfloat16*)(base + 8192);
    short8 af[4], bfr[4];
#pragma unroll
    for (int mt = 0; mt < 4; ++mt)
      af[mt] = *(const short8*)(As + (wr * 64 + mt * 16 + fr) * 32 + fqs * 8);
#pragma unroll
    for (int nt = 0; nt < 4; ++nt)
      bfr[nt] = *(const short8*)(Bs + (wc * 64 + nt * 16 + fr) * 32 + fqs * 8);
#pragma unroll
    for (int mt = 0; mt < 4; ++mt)
#pragma unroll
      for (int nt = 0; nt < 4; ++nt)
        acc[mt][nt] = __builtin_amdgcn_mfma_f32_16x16x32_bf16(
            af[mt], bfr[nt], acc[mt][nt], 0, 0, 0);
  };

  char* buf0 = smem;
  char* buf1 = smem + 16384;
  stage(0, buf0);
  __syncthreads();
  for (int kt = 0; kt < 16; kt += 2) {
    stage(kt + 1, buf1);
    compute(buf0);
    __syncthreads();
    if (kt + 2 < 16) stage(kt + 2, buf0);
    compute(buf1);
    __syncthreads();
  }

  __hip_bfloat16* Oc = (__hip_bfloat16*)smem;  // [16][1024] slot-swizzled
#pragma unroll
  for (int mt = 0; mt < 4; ++mt) {
#pragma unroll
    for (int nt = 0; nt < 4; ++nt) {
      const int orow_b = wr * 64 + mt * 16 + fq * 4;
      const int ocol = wc * 64 + nt * 16 + fr;
#pragma unroll
      for (int r = 0; r < 4; ++r) {
        const int orow = orow_b + r;
        const int cell = ((orow >> 5) << 2) + (ocol >> 5);
        const int kk = ((orow & 31) << 5) + (ocol & 31);
        const int sw = ((((kk >> 3) ^ (cell & 7)) << 3) | (kk & 7));
        Oc[cell * 1024 + sw] = __float2bfloat16(acc[mt][nt][r]);
      }
    }
  }
  __syncthreads();

  f32x4 zacc0 = fzero, zacc1 = fzero;
  const int zt0 = wave * 2;
  const int xr = fr & 7;
  for (int kk = 0; kk < 32; ++kk) {
    const int slot = kk * 4 + fq;
    const short8 oa = *(const short8*)(Oc + fr * 1024 + ((slot ^ xr) << 3));
    const short8 wb0 =
        *(const short8*)(Wf + (size_t)((zt0 + 0) * 16 + fr) * 1024 + kk * 32 + fq * 8);
    const short8 wb1 =
        *(const short8*)(Wf + (size_t)((zt0 + 1) * 16 + fr) * 1024 + kk * 32 + fq * 8);
    zacc0 = __builtin_amdgcn_mfma_f32_16x16x32_bf16(oa, wb0, zacc0, 0, 0, 0);
    zacc1 = __builtin_amdgcn_mfma_f32_16x16x32_bf16(oa, wb1, zacc1, 0, 0, 0);
  }

  const int i0 = bi * 4, j0 = bj * 4;
#pragma unroll
  for (int t = 0; t < 2; ++t) {
    const int zcol = (zt0 + t) * 16 + fr;
    const float bz = b_final[zcol];
    const f32x4 za = t ? zacc1 : zacc0;
#pragma unroll
    for (int r = 0; r < 4; ++r) {
      const int cell = fq * 4 + r;
      const int li = cell >> 2, lj = cell & 3;
      out[((size_t)(i0 + li) * S_DIM + (j0 + lj)) * CZ_DIM + zcol] = za[r] + bz;
    }
  }
}

extern "C" void kernel_launch(void* const* d_in, const int* in_sizes, int n_in,
                              void* d_out, int out_size, void* d_ws, size_t ws_size,
                              hipStream_t stream) {
  const float* m_si = (const float*)d_in[0];
  const float* ln_g = (const float*)d_in[1];
  const float* ln_b = (const float*)d_in[2];
  const float* w_ab = (const float*)d_in[3];
  const float* w_final = (const float*)d_in[4];
  const float* b_final = (const float*)d_in[5];
  float* out = (float*)d_out;

  char* ws = (char*)d_ws;
  __hip_bfloat16* Abt = (__hip_bfloat16*)ws;                                // 12.58 MB
  __hip_bfloat16* Bbt = (__hip_bfloat16*)(ws + (size_t)MROWS * N_DIM * 2);  // 12.58 MB
  __hip_bfloat16* Wf = (__hip_bfloat16*)(ws + (size_t)MROWS * N_DIM * 4);   // 256 KB
  const size_t base = (size_t)MROWS * N_DIM * 4 + 262144;
  __hip_bfloat16* Og = (__hip_bfloat16*)(ws + base);

  prep_kernel<<<dim3(2, S_DIM), 256, 0, stream>>>(m_si, ln_g, ln_b, w_ab, Abt, Bbt);
  conv_wf<<<dim3((CZ_DIM * 1024) / 256), 256, 0, stream>>>(w_final, Wf);

  // Pick the largest O slab that fits. Start at nslab=2: a 151 MB slab stays
  // L3-resident (256 MB) between the opm write and the zgemm read; nslab=1
  // (302 MB) would spill the O round-trip to HBM even if ws allowed it.
  static const int cands[] = {2, 3, 4, 6, 8, 12, 16, 24, 32};
  int nslab = 0;
  for (int c : cands) {
    if (base + ((size_t)NCELL / c) * 1024 * 2 <= ws_size) { nslab = c; break; }
  }

  if (nslab) {
    const int biPer = 96 / nslab;                    // block-rows per slab
    const int cellsPer = NCELL / nslab;              // cells per slab
    for (int s = 0; s < nslab; ++s) {
      opm_main<<<dim3(96, biPer), 256, 0, stream>>>(Abt, Bbt, Og, s * biPer);
      zgemm<<<dim3(cellsPer / 128), 256, 0, stream>>>(
          Og, Wf, b_final, out + (size_t)s * cellsPer * CZ_DIM);
    }
  } else {
    fused_opm<<<dim3(96, 96), 256, 0, stream>>>(Abt, Bbt, Wf, b_final, out);
  }
}